// Round 17
// baseline (3903.544 us; speedup 1.0000x reference)
//
#include <hip/hip_runtime.h>

constexpr int N = 20000;
constexpr int E = 320000;
constexpr int Bc = 2;
constexpr int D = 64;
constexpr int L = 25;
constexpr float EPS = 1e-5f;

typedef __attribute__((ext_vector_type(8))) short short8;
typedef __attribute__((ext_vector_type(4))) float f32x4;

__device__ __forceinline__ unsigned short f2bf(float f) {
  unsigned u = __float_as_uint(f);
  u += 0x7fff + ((u >> 16) & 1);   // RNE
  return (unsigned short)(u >> 16);
}

// ---------------- CSR build (once per launch; edges shared by both graphs) ----------------
__global__ void hist_kernel(const int* __restrict__ row, int* __restrict__ deg) {
  int e = blockIdx.x * blockDim.x + threadIdx.x;
  if (e < E) atomicAdd(&deg[row[e]], 1);
}

__global__ __launch_bounds__(1024) void scan_kernel(const int* __restrict__ deg,
                                                    int* __restrict__ row_start,
                                                    int* __restrict__ cursor) {
  __shared__ int s[1024];
  const int t = threadIdx.x;
  constexpr int CH = (N + 1023) / 1024;
  int base = t * CH;
  int sum = 0;
  for (int k = 0; k < CH; ++k) {
    int idx = base + k;
    if (idx < N) sum += deg[idx];
  }
  s[t] = sum;
  __syncthreads();
  for (int off = 1; off < 1024; off <<= 1) {
    int v = (t >= off) ? s[t - off] : 0;
    __syncthreads();
    s[t] += v;
    __syncthreads();
  }
  int excl = s[t] - sum;
  for (int k = 0; k < CH; ++k) {
    int idx = base + k;
    if (idx < N) {
      row_start[idx] = excl;
      cursor[idx] = excl;
      excl += deg[idx];
    }
  }
  if (t == 1023) row_start[N] = s[1023];
}

__global__ void scatter_kernel(const int* __restrict__ row, int* __restrict__ cursor,
                               int* __restrict__ edge_order) {
  int e = blockIdx.x * blockDim.x + threadIdx.x;
  if (e < E) {
    int p = atomicAdd(&cursor[row[e]], 1);
    edge_order[p] = e;
  }
}

__global__ void sortmap_kernel(const int* __restrict__ edge_order,
                               const int* __restrict__ col,
                               const float* __restrict__ eattr,
                               int* __restrict__ col_s, float2* __restrict__ ea_s) {
  int p = blockIdx.x * blockDim.x + threadIdx.x;
  if (p < E) {
    int eid = edge_order[p];
    col_s[p] = col[eid];
    ea_s[p] = *(const float2*)&eattr[2 * (size_t)eid];
  }
}

// ---------------- uw pre-pack: bf16 MFMA B-fragments, once ----------------
__global__ __launch_bounds__(512) void packuw_kernel(
    const float* __restrict__ up_w, unsigned short* __restrict__ uwpack) {
  const int f = blockIdx.x;   // 0..15
  const int l = blockIdx.y;   // 0..L-1
  const int t = threadIdx.x;  // 0..511
  const int ln = t >> 3, i = t & 7;
  int nt = f >> 2, ks = f & 3;
  int k = ks * 32 + (ln >> 4) * 8 + i, n = nt * 16 + (ln & 15);
  uwpack[((size_t)l * 16 + f) * 512 + ln * 8 + i] =
      f2bf(up_w[(size_t)l * 128 * 64 + (size_t)k * 64 + n]);
}

// ---------------- encoder ----------------
__global__ __launch_bounds__(512) void encoder_kernel(
    const float* __restrict__ x, const float* __restrict__ enc_w,
    const float* __restrict__ enc_b, float* __restrict__ h,
    unsigned short* __restrict__ hbf) {
  int idx = blockIdx.x * blockDim.x + threadIdx.x;
  if (idx >= Bc * N * D) return;
  int j = idx & (D - 1);
  int bn = idx >> 6;
  const float* xp = x + (size_t)bn * 3;
  float v = enc_b[j] + xp[0] * enc_w[j] + xp[1] * enc_w[D + j] + xp[2] * enc_w[2 * D + j];
  h[idx] = v;
  hbf[idx] = f2bf(v);
}

// ---------------- fused layer kernel: edge MLP + aggregate + node update ----------------
// R15 base + R17 psum trick: accumulate SUM of relu(LN(.)) per node in registers
// (linearity: sum_e(P@W2 + b2) = (sum_e P)@W2 + deg*b2); GEMV2 runs ONCE per wave,
// batched over the 4 nodes, using ONLY the proven aggs store/read index patterns.
// Removes per tile: 16 f2bf, 16 LDS writes, 2 LDS reads, 8 MFMA. LDS 48 -> 32 KB.
constexpr int GPN = 4;              // nodes per wave
constexpr int GPG = N / GPN;        // 5000 groups per graph
constexpr int NGRP = GPG * Bc;      // 10000
constexpr int EWB = 8;              // waves per block
constexpr int ETPB = EWB * 64;      // 512

__global__ __launch_bounds__(ETPB, 4) void layer_kernel(
    const unsigned short* __restrict__ hbf_old, unsigned short* __restrict__ hbf_new,
    float* __restrict__ h,
    const int* __restrict__ col_s, const float2* __restrict__ ea_s,
    const int* __restrict__ row_start,
    const float* __restrict__ w1, const float* __restrict__ b1,
    const float* __restrict__ g1, const float* __restrict__ be1,
    const float* __restrict__ w2, const float* __restrict__ b2,
    const unsigned short* __restrict__ uwpack_l, const float* __restrict__ ub,
    const float* __restrict__ ug, const float* __restrict__ ube) {
  __shared__ __align__(16) char smem[24576 + EWB * 1024];  // 32 KB
  unsigned short* w1f = (unsigned short*)smem;             // 16 KB (16 B-frags)
  unsigned short* w2f = (unsigned short*)(smem + 16384);   // 8 KB  (8 B-frags)

  const int tid = threadIdx.x, lane = tid & 63, w = tid >> 6;
  const int cl = lane & 15, hg = lane >> 4;
  float* aggs = (float*)(smem + 24576 + w * 1024);  // per-wave [GPN][64] f32

  // B-frag staging: frag f; value wt[k][n], k=ks*32+(ln>>4)*8+i, n=nt*16+(ln&15)
  for (int idx = tid; idx < 16 * 512; idx += ETPB) {
    int f = idx >> 9, rem = idx & 511, ln = rem >> 3, i = rem & 7;
    int nt = f >> 2, ks = f & 3;
    int k = ks * 32 + (ln >> 4) * 8 + i, n = nt * 16 + (ln & 15);
    w1f[idx] = f2bf(w1[k * 64 + n]);
  }
  for (int idx = tid; idx < 8 * 512; idx += ETPB) {
    int f = idx >> 9, rem = idx & 511, ln = rem >> 3, i = rem & 7;
    int nt = f >> 1, ks = f & 1;
    int k = ks * 32 + (ln >> 4) * 8 + i, n = nt * 16 + (ln & 15);
    w2f[idx] = f2bf(w2[k * 64 + n]);
  }
  __syncthreads();  // only block-wide barrier

  float b1c[4], g1c[4], be1c[4], b2c[4], wA[4], wB[4], ubc[4], ugc[4], ubec[4];
#pragma unroll
  for (int nt = 0; nt < 4; ++nt) {
    int c = nt * 16 + cl;
    b1c[nt] = b1[c]; g1c[nt] = g1[c]; be1c[nt] = be1[c]; b2c[nt] = b2[c];
    wA[nt] = w1[128 * 64 + c]; wB[nt] = w1[129 * 64 + c];
    ubc[nt] = ub[c]; ugc[nt] = ug[c]; ubec[nt] = ube[c];
  }
  const short8* w1v = (const short8*)w1f;
  const short8* w2v = (const short8*)w2f;
  const short8* uwv = (const short8*)uwpack_l;   // L2-hot global frags

  const int gw = __builtin_amdgcn_readfirstlane(blockIdx.x * EWB + w);
  if (gw >= NGRP) return;
  const int g = (gw >= GPG) ? 1 : 0;
  const int nb = (gw - g * GPG) * GPN;
  const unsigned short* hb = hbf_old + (size_t)g * N * 64;

  int rs[GPN + 1];
#pragma unroll
  for (int k = 0; k <= GPN; ++k) rs[k] = row_start[nb + k];

  // zero per-wave psum staging (covers empty nodes)
#pragma unroll
  for (int k = 0; k < GPN; ++k) aggs[k * 64 + lane] = 0.f;

  // ================= edge phase: GEMV1 + LN + register psum =================
  for (int k = 0; k < GPN; ++k) {
    const int es = rs[k], ee = rs[k + 1];
    if (ee == es) continue;
    float macc[4] = {0.f, 0.f, 0.f, 0.f};   // psum partial: channel nt*16+cl over my edges

    // node-row A-frags (broadcast loads, L1)
    const unsigned short* pn = hb + (((size_t)(nb + k)) << 6) + hg * 8;
    const short8 av0 = *(const short8*)pn;
    const short8 av1 = *(const short8*)(pn + 32);

    // first tile gather
    int pos = es + cl; if (pos >= ee) pos = ee - 1;
    float2 eaC = ea_s[pos];
    const unsigned short* pc0 = hb + (((size_t)col_s[pos]) << 6) + hg * 8;
    short8 a2C = *(const short8*)pc0;
    short8 a3C = *(const short8*)(pc0 + 32);

    for (int ts = es; ts < ee; ts += 16) {
      const bool hasN = (ts + 16) < ee;
      float2 eaN; short8 a2N, a3N;
      if (hasN) {  // within-node prefetch (wave-uniform branch)
        int p2 = ts + 16 + cl; if (p2 >= ee) p2 = ee - 1;
        eaN = ea_s[p2];
        const unsigned short* pc = hb + (((size_t)col_s[p2]) << 6) + hg * 8;
        a2N = *(const short8*)pc;
        a3N = *(const short8*)(pc + 32);
      }

      // GEMV1: K=128 (16 MFMA)
      f32x4 acc[4];
#pragma unroll
      for (int nt = 0; nt < 4; ++nt) acc[nt] = (f32x4){0.f, 0.f, 0.f, 0.f};
      __builtin_amdgcn_s_setprio(1);
#pragma unroll
      for (int nt = 0; nt < 4; ++nt)
        acc[nt] = __builtin_amdgcn_mfma_f32_16x16x32_bf16(av0, w1v[(nt * 4 + 0) * 64 + lane], acc[nt], 0, 0, 0);
#pragma unroll
      for (int nt = 0; nt < 4; ++nt)
        acc[nt] = __builtin_amdgcn_mfma_f32_16x16x32_bf16(av1, w1v[(nt * 4 + 1) * 64 + lane], acc[nt], 0, 0, 0);
#pragma unroll
      for (int nt = 0; nt < 4; ++nt)
        acc[nt] = __builtin_amdgcn_mfma_f32_16x16x32_bf16(a2C, w1v[(nt * 4 + 2) * 64 + lane], acc[nt], 0, 0, 0);
#pragma unroll
      for (int nt = 0; nt < 4; ++nt)
        acc[nt] = __builtin_amdgcn_mfma_f32_16x16x32_bf16(a3C, w1v[(nt * 4 + 3) * 64 + lane], acc[nt], 0, 0, 0);
      __builtin_amdgcn_s_setprio(0);

      // epilogue: bias + eattr; fused (sum,sumsq) LN; relu; accumulate into psum regs
      const int vleft = ee - ts - hg * 4;
#pragma unroll
      for (int r = 0; r < 4; ++r) {
        const int edge = hg * 4 + r;
        float e0 = __shfl(eaC.x, edge, 64);
        float e1 = __shfl(eaC.y, edge, 64);
        float v[4];
#pragma unroll
        for (int nt = 0; nt < 4; ++nt)
          v[nt] = acc[nt][r] + b1c[nt] + e0 * wA[nt] + e1 * wB[nt];
        float s = v[0] + v[1] + v[2] + v[3];
        float q = v[0] * v[0] + v[1] * v[1] + v[2] * v[2] + v[3] * v[3];
#pragma unroll
        for (int o = 1; o < 16; o <<= 1) {
          s += __shfl_xor(s, o, 64);
          q += __shfl_xor(q, o, 64);
        }
        float mu = s * (1.f / 64.f);
        float var = fmaf(-mu, mu, q * (1.f / 64.f));
        float rsq = rsqrtf(var + EPS);
        if (r < vleft) {
#pragma unroll
          for (int nt = 0; nt < 4; ++nt)
            macc[nt] += fmaxf((v[nt] - mu) * rsq * g1c[nt] + be1c[nt], 0.f);
        }
      }

      if (hasN) { eaC = eaN; a2C = a2N; a3C = a3N; }
    }

    // node-k finalize (PROVEN R12 pattern): butterfly over hg, store psum to swizzled aggs
    float fin[4];
#pragma unroll
    for (int nt = 0; nt < 4; ++nt) {
      float s = macc[nt];
      s += __shfl_xor(s, 16, 64);
      s += __shfl_xor(s, 32, 64);
      fin[nt] = s;
    }
    float sv = (hg == 0) ? fin[0] : (hg == 1) ? fin[1] : (hg == 2) ? fin[2] : fin[3];
    aggs[k * 64 + ((hg * 16 + cl) ^ (k << 3))] = sv;
  }

  // ====== wave-end batched GEMV2: aggr[node] = psum[node] @ W2 + deg*b2 (8 MFMA) ======
  {
    const int nc = (cl < GPN) ? cl : (GPN - 1);   // A row m = cl (node); rows >= GPN junk
    // psum A-frags via the PROVEN read pattern (same as node-phase av[2]/av[3]):
    // k-slices 0..31 and 32..63, float idx nc*64 + ((base) ^ (nc<<3)) + i
    const int i0 = nc * 64 + ((hg * 8) ^ (nc << 3));
    const int i1 = nc * 64 + ((32 + hg * 8) ^ (nc << 3));
    float4 q0 = *(const float4*)&aggs[i0];
    float4 q1 = *(const float4*)&aggs[i0 + 4];
    float4 q2 = *(const float4*)&aggs[i1];
    float4 q3 = *(const float4*)&aggs[i1 + 4];
    short8 p0, p1;
    {
      union { short8 s; unsigned short u[8]; } t0, t1;
      t0.u[0] = f2bf(q0.x); t0.u[1] = f2bf(q0.y); t0.u[2] = f2bf(q0.z); t0.u[3] = f2bf(q0.w);
      t0.u[4] = f2bf(q1.x); t0.u[5] = f2bf(q1.y); t0.u[6] = f2bf(q1.z); t0.u[7] = f2bf(q1.w);
      t1.u[0] = f2bf(q2.x); t1.u[1] = f2bf(q2.y); t1.u[2] = f2bf(q2.z); t1.u[3] = f2bf(q2.w);
      t1.u[4] = f2bf(q3.x); t1.u[5] = f2bf(q3.y); t1.u[6] = f2bf(q3.z); t1.u[7] = f2bf(q3.w);
      p0 = t0.s; p1 = t1.s;
    }

    f32x4 agg[4];
    __builtin_amdgcn_s_setprio(1);
#pragma unroll
    for (int nt = 0; nt < 4; ++nt) {
      f32x4 t = __builtin_amdgcn_mfma_f32_16x16x32_bf16(
          p0, w2v[(nt * 2 + 0) * 64 + lane], (f32x4){0.f, 0.f, 0.f, 0.f}, 0, 0, 0);
      agg[nt] = __builtin_amdgcn_mfma_f32_16x16x32_bf16(
          p1, w2v[(nt * 2 + 1) * 64 + lane], t, 0, 0, 0);
    }
    __builtin_amdgcn_s_setprio(0);

    // C layout: row = node = hg*4+r -> nodes 0..3 live at hg==0. Write back to aggs
    // with the PROVEN store key (channel ^ (node<<3), float domain).
    if (hg == 0) {
#pragma unroll
      for (int r = 0; r < 4; ++r) {
        const float degf = (float)(rs[r + 1] - rs[r]);
#pragma unroll
        for (int nt = 0; nt < 4; ++nt) {
          int c = nt * 16 + cl;
          aggs[r * 64 + (c ^ (r << 3))] = agg[nt][r] + degf * b2c[nt];
        }
      }
    }
  }

  // ================= node phase: u = relu(LN([h,aggr]@uw+ub)); h += u =================
  {
    const int nc = (cl < GPN) ? cl : (GPN - 1);   // A row m = cl; rows >= GPN discarded
    const unsigned short* ph = hb + (((size_t)(nb + nc)) << 6) + hg * 8;
    short8 av[4];
    av[0] = *(const short8*)ph;
    av[1] = *(const short8*)(ph + 32);
    // aggr slices from swizzled LDS (contiguous after XOR since key is mult of 8)
    const int i0 = nc * 64 + ((hg * 8) ^ (nc << 3));
    const int i1 = nc * 64 + ((32 + hg * 8) ^ (nc << 3));
    float4 q0 = *(const float4*)&aggs[i0];
    float4 q1 = *(const float4*)&aggs[i0 + 4];
    float4 q2 = *(const float4*)&aggs[i1];
    float4 q3 = *(const float4*)&aggs[i1 + 4];
    {
      union { short8 s; unsigned short u[8]; } t2, t3;
      t2.u[0] = f2bf(q0.x); t2.u[1] = f2bf(q0.y); t2.u[2] = f2bf(q0.z); t2.u[3] = f2bf(q0.w);
      t2.u[4] = f2bf(q1.x); t2.u[5] = f2bf(q1.y); t2.u[6] = f2bf(q1.z); t2.u[7] = f2bf(q1.w);
      t3.u[0] = f2bf(q2.x); t3.u[1] = f2bf(q2.y); t3.u[2] = f2bf(q2.z); t3.u[3] = f2bf(q2.w);
      t3.u[4] = f2bf(q3.x); t3.u[5] = f2bf(q3.y); t3.u[6] = f2bf(q3.z); t3.u[7] = f2bf(q3.w);
      av[2] = t2.s; av[3] = t3.s;
    }

    f32x4 acc[4];
#pragma unroll
    for (int nt = 0; nt < 4; ++nt) acc[nt] = (f32x4){0.f, 0.f, 0.f, 0.f};
    __builtin_amdgcn_s_setprio(1);
#pragma unroll
    for (int ks = 0; ks < 4; ++ks) {
#pragma unroll
      for (int nt = 0; nt < 4; ++nt)
        acc[nt] = __builtin_amdgcn_mfma_f32_16x16x32_bf16(
            av[ks], uwv[(nt * 4 + ks) * 64 + lane], acc[nt], 0, 0, 0);
    }
    __builtin_amdgcn_s_setprio(0);

    // epilogue: rows 0..GPN-1 live in hg==0 (row = hg*4+r)
#pragma unroll
    for (int r = 0; r < 4; ++r) {
      float v[4];
#pragma unroll
      for (int nt = 0; nt < 4; ++nt) v[nt] = acc[nt][r] + ubc[nt];
      float s = v[0] + v[1] + v[2] + v[3];
      float q = v[0] * v[0] + v[1] * v[1] + v[2] * v[2] + v[3] * v[3];
#pragma unroll
      for (int o = 1; o < 16; o <<= 1) {
        s += __shfl_xor(s, o, 64);
        q += __shfl_xor(q, o, 64);
      }
      float mu = s * (1.f / 64.f);
      float var = fmaf(-mu, mu, q * (1.f / 64.f));
      float rsq = rsqrtf(var + EPS);
      if (hg == 0) {
        const size_t nrow = ((size_t)(g * N + nb + r)) << 6;
#pragma unroll
        for (int nt = 0; nt < 4; ++nt) {
          int c = nt * 16 + cl;
          float u = fmaxf((v[nt] - mu) * rsq * ugc[nt] + ubec[nt], 0.f);
          float nv = h[nrow + c] + u;    // exclusive ownership -> in-place safe
          h[nrow + c] = nv;
          hbf_new[nrow + c] = f2bf(nv);
        }
      }
    }
  }
}

// ---------------- decoder ----------------
__global__ __launch_bounds__(512) void decoder_kernel(
    const float* __restrict__ h,
    const float* __restrict__ dw1, const float* __restrict__ db1,
    const float* __restrict__ dw2, const float* __restrict__ db2,
    float* __restrict__ out) {
  __shared__ __align__(16) float w1s[64 * 32];
  __shared__ float w2s[64];
  __shared__ float b1s[32];
  __shared__ float hs[8][64];
  const int tid = threadIdx.x;
  const int lane = tid & 63;
  const int w = tid >> 6;

  for (int idx = tid; idx < 64 * 32; idx += 512) w1s[idx] = dw1[idx];
  if (tid < 64) w2s[tid] = dw2[tid];
  if (tid < 32) b1s[tid] = db1[tid];
  const float ob0 = db2[0], ob1 = db2[1];
  __syncthreads();

  const int total = Bc * N;
  const int per_iter = gridDim.x * 8;
  const int niter = (total + per_iter - 1) / per_iter;
  const int wave_global = blockIdx.x * 8 + w;

  for (int it = 0; it < niter; ++it) {
    const int i = it * per_iter + wave_global;
    if (i < total) {
      hs[w][lane] = h[((size_t)i << 6) + lane];
      float s1 = 0.f;
      if (lane < 32) {
        s1 = b1s[lane];
        for (int k = 0; k < 64; ++k) s1 = fmaf(hs[w][k], w1s[k * 32 + lane], s1);
        s1 = fmaxf(s1, 0.f);
      }
      float c0 = (lane < 32) ? s1 * w2s[lane * 2]     : 0.f;
      float c1 = (lane < 32) ? s1 * w2s[lane * 2 + 1] : 0.f;
#pragma unroll
      for (int off = 16; off > 0; off >>= 1) {
        c0 += __shfl_xor(c0, off, 64);
        c1 += __shfl_xor(c1, off, 64);
      }
      if (lane == 0) {
        out[(size_t)i * 2]     = c0 + ob0;
        out[(size_t)i * 2 + 1] = c1 + ob1;
      }
    }
  }
}

extern "C" void kernel_launch(void* const* d_in, const int* in_sizes, int n_in,
                              void* d_out, int out_size, void* d_ws, size_t ws_size,
                              hipStream_t stream) {
  const float* x        = (const float*)d_in[0];
  const int*   ei       = (const int*)d_in[1];
  const float* eattr    = (const float*)d_in[2];
  const float* enc_w    = (const float*)d_in[3];
  const float* enc_b    = (const float*)d_in[4];
  const float* msg_w1   = (const float*)d_in[5];
  const float* msg_b1   = (const float*)d_in[6];
  const float* msg_ln_g = (const float*)d_in[7];
  const float* msg_ln_b = (const float*)d_in[8];
  const float* msg_w2   = (const float*)d_in[9];
  const float* msg_b2   = (const float*)d_in[10];
  const float* up_w     = (const float*)d_in[11];
  const float* up_b     = (const float*)d_in[12];
  const float* up_ln_g  = (const float*)d_in[13];
  const float* up_ln_b  = (const float*)d_in[14];
  const float* dw1      = (const float*)d_in[15];
  const float* db1      = (const float*)d_in[16];
  const float* dw2      = (const float*)d_in[17];
  const float* db2      = (const float*)d_in[18];
  float* out = (float*)d_out;

  // workspace: h (f32, in-place), hbf0/hbf1 (bf16 ping-pong), uw prepack, sorted arrays, CSR
  float* h              = (float*)d_ws;
  unsigned short* hbf0  = (unsigned short*)(h + (size_t)Bc * N * D);
  unsigned short* hbf1  = hbf0 + (size_t)Bc * N * D;
  unsigned short* uwpack = hbf1 + (size_t)Bc * N * D;            // L*16*512 bf16
  float2* ea_sv         = (float2*)(uwpack + (size_t)L * 16 * 512);
  int* col_sv           = (int*)(ea_sv + E);
  int* edge_order       = col_sv + E;
  int* deg              = edge_order + E;
  int* row_start        = deg + N;
  int* cursor           = row_start + N + 1;

  const int* row = ei;
  const int* col = ei + E;

  hipMemsetAsync(deg, 0, N * sizeof(int), stream);
  hist_kernel<<<(E + 255) / 256, 256, 0, stream>>>(row, deg);
  scan_kernel<<<1, 1024, 0, stream>>>(deg, row_start, cursor);
  scatter_kernel<<<(E + 255) / 256, 256, 0, stream>>>(row, cursor, edge_order);
  sortmap_kernel<<<(E + 255) / 256, 256, 0, stream>>>(edge_order, col, eattr, col_sv, ea_sv);
  packuw_kernel<<<dim3(16, L), 512, 0, stream>>>(up_w, uwpack);
  encoder_kernel<<<(Bc * N * D + 511) / 512, 512, 0, stream>>>(x, enc_w, enc_b, h, hbf0);

  unsigned short* hbufs[2] = {hbf0, hbf1};
  for (int l = 0; l < L; ++l) {
    layer_kernel<<<(NGRP + EWB - 1) / EWB, ETPB, 0, stream>>>(
        hbufs[l & 1], hbufs[(l + 1) & 1], h,
        col_sv, ea_sv, row_start,
        msg_w1 + (size_t)l * 130 * 64, msg_b1 + l * 64,
        msg_ln_g + l * 64, msg_ln_b + l * 64,
        msg_w2 + (size_t)l * 64 * 64, msg_b2 + l * 64,
        uwpack + (size_t)l * 16 * 512, up_b + l * 64,
        up_ln_g + l * 64, up_ln_b + l * 64);
  }

  decoder_kernel<<<512, 512, 0, stream>>>(h, dw1, db1, dw2, db2, out);
}

// Round 18
// 2616.114 us; speedup vs baseline: 1.4921x; 1.4921x over previous
//
#include <hip/hip_runtime.h>

constexpr int N = 20000;
constexpr int E = 320000;
constexpr int Bc = 2;
constexpr int D = 64;
constexpr int L = 25;
constexpr float EPS = 1e-5f;

typedef __attribute__((ext_vector_type(8))) short short8;
typedef __attribute__((ext_vector_type(4))) float f32x4;

__device__ __forceinline__ unsigned short f2bf(float f) {
  unsigned u = __float_as_uint(f);
  u += 0x7fff + ((u >> 16) & 1);   // RNE
  return (unsigned short)(u >> 16);
}

// ---------------- CSR build (once per launch; edges shared by both graphs) ----------------
__global__ void hist_kernel(const int* __restrict__ row, int* __restrict__ deg) {
  int e = blockIdx.x * blockDim.x + threadIdx.x;
  if (e < E) atomicAdd(&deg[row[e]], 1);
}

__global__ __launch_bounds__(1024) void scan_kernel(const int* __restrict__ deg,
                                                    int* __restrict__ row_start,
                                                    int* __restrict__ cursor) {
  __shared__ int s[1024];
  const int t = threadIdx.x;
  constexpr int CH = (N + 1023) / 1024;
  int base = t * CH;
  int sum = 0;
  for (int k = 0; k < CH; ++k) {
    int idx = base + k;
    if (idx < N) sum += deg[idx];
  }
  s[t] = sum;
  __syncthreads();
  for (int off = 1; off < 1024; off <<= 1) {
    int v = (t >= off) ? s[t - off] : 0;
    __syncthreads();
    s[t] += v;
    __syncthreads();
  }
  int excl = s[t] - sum;
  for (int k = 0; k < CH; ++k) {
    int idx = base + k;
    if (idx < N) {
      row_start[idx] = excl;
      cursor[idx] = excl;
      excl += deg[idx];
    }
  }
  if (t == 1023) row_start[N] = s[1023];
}

__global__ void scatter_kernel(const int* __restrict__ row, int* __restrict__ cursor,
                               int* __restrict__ edge_order) {
  int e = blockIdx.x * blockDim.x + threadIdx.x;
  if (e < E) {
    int p = atomicAdd(&cursor[row[e]], 1);
    edge_order[p] = e;
  }
}

__global__ void sortmap_kernel(const int* __restrict__ edge_order,
                               const int* __restrict__ col,
                               const float* __restrict__ eattr,
                               int* __restrict__ col_s, float2* __restrict__ ea_s) {
  int p = blockIdx.x * blockDim.x + threadIdx.x;
  if (p < E) {
    int eid = edge_order[p];
    col_s[p] = col[eid];
    ea_s[p] = *(const float2*)&eattr[2 * (size_t)eid];
  }
}

// ---------------- uw pre-pack: bf16 MFMA B-fragments, once ----------------
__global__ __launch_bounds__(512) void packuw_kernel(
    const float* __restrict__ up_w, unsigned short* __restrict__ uwpack) {
  const int f = blockIdx.x;   // 0..15
  const int l = blockIdx.y;   // 0..L-1
  const int t = threadIdx.x;  // 0..511
  const int ln = t >> 3, i = t & 7;
  int nt = f >> 2, ks = f & 3;
  int k = ks * 32 + (ln >> 4) * 8 + i, n = nt * 16 + (ln & 15);
  uwpack[((size_t)l * 16 + f) * 512 + ln * 8 + i] =
      f2bf(up_w[(size_t)l * 128 * 64 + (size_t)k * 64 + n]);
}

// ---------------- encoder ----------------
__global__ __launch_bounds__(512) void encoder_kernel(
    const float* __restrict__ x, const float* __restrict__ enc_w,
    const float* __restrict__ enc_b, float* __restrict__ h,
    unsigned short* __restrict__ hbf) {
  int idx = blockIdx.x * blockDim.x + threadIdx.x;
  if (idx >= Bc * N * D) return;
  int j = idx & (D - 1);
  int bn = idx >> 6;
  const float* xp = x + (size_t)bn * 3;
  float v = enc_b[j] + xp[0] * enc_w[j] + xp[1] * enc_w[D + j] + xp[2] * enc_w[2 * D + j];
  h[idx] = v;
  hbf[idx] = f2bf(v);
}

// ---------------- fused layer kernel: edge MLP + aggregate + node update ----------------
// R15 base + R18: next-node col_s/ea prefetch ONLY (4 regs; h-gather NOT prefetched --
// that spilled in R13). Removes the col_s hop from the node-boundary critical chain.
constexpr int GPN = 4;              // nodes per wave
constexpr int GPG = N / GPN;        // 5000 groups per graph
constexpr int NGRP = GPG * Bc;      // 10000
constexpr int EWB = 8;              // waves per block
constexpr int ETPB = EWB * 64;      // 512

__global__ __launch_bounds__(ETPB, 4) void layer_kernel(
    const unsigned short* __restrict__ hbf_old, unsigned short* __restrict__ hbf_new,
    float* __restrict__ h,
    const int* __restrict__ col_s, const float2* __restrict__ ea_s,
    const int* __restrict__ row_start,
    const float* __restrict__ w1, const float* __restrict__ b1,
    const float* __restrict__ g1, const float* __restrict__ be1,
    const float* __restrict__ w2, const float* __restrict__ b2,
    const unsigned short* __restrict__ uwpack_l, const float* __restrict__ ub,
    const float* __restrict__ ug, const float* __restrict__ ube) {
  __shared__ __align__(16) char smem[24576 + EWB * 3072];  // 48 KB -> 3 blocks/CU
  unsigned short* w1f = (unsigned short*)smem;             // 16 KB (16 B-frags)
  unsigned short* w2f = (unsigned short*)(smem + 16384);   // 8 KB  (8 B-frags)

  const int tid = threadIdx.x, lane = tid & 63, w = tid >> 6;
  const int cl = lane & 15, hg = lane >> 4;
  char* pw = smem + 24576 + w * 3072;        // per-wave P staging (2 KB)
  float* aggs = (float*)(pw + 2048);         // per-wave aggr [GPN][64] f32 (1 KB)

  // B-frag staging: frag f; value wt[k][n], k=ks*32+(ln>>4)*8+i, n=nt*16+(ln&15)
  for (int idx = tid; idx < 16 * 512; idx += ETPB) {
    int f = idx >> 9, rem = idx & 511, ln = rem >> 3, i = rem & 7;
    int nt = f >> 2, ks = f & 3;
    int k = ks * 32 + (ln >> 4) * 8 + i, n = nt * 16 + (ln & 15);
    w1f[idx] = f2bf(w1[k * 64 + n]);
  }
  for (int idx = tid; idx < 8 * 512; idx += ETPB) {
    int f = idx >> 9, rem = idx & 511, ln = rem >> 3, i = rem & 7;
    int nt = f >> 1, ks = f & 1;
    int k = ks * 32 + (ln >> 4) * 8 + i, n = nt * 16 + (ln & 15);
    w2f[idx] = f2bf(w2[k * 64 + n]);
  }
  __syncthreads();  // only block-wide barrier

  float b1c[4], g1c[4], be1c[4], b2c[4], wA[4], wB[4], ubc[4], ugc[4], ubec[4];
#pragma unroll
  for (int nt = 0; nt < 4; ++nt) {
    int c = nt * 16 + cl;
    b1c[nt] = b1[c]; g1c[nt] = g1[c]; be1c[nt] = be1[c]; b2c[nt] = b2[c];
    wA[nt] = w1[128 * 64 + c]; wB[nt] = w1[129 * 64 + c];
    ubc[nt] = ub[c]; ugc[nt] = ug[c]; ubec[nt] = ube[c];
  }
  const short8* w1v = (const short8*)w1f;
  const short8* w2v = (const short8*)w2f;
  const short8* uwv = (const short8*)uwpack_l;   // L2-hot global frags

  const int gw = __builtin_amdgcn_readfirstlane(blockIdx.x * EWB + w);
  if (gw >= NGRP) return;
  const int g = (gw >= GPG) ? 1 : 0;
  const int nb = (gw - g * GPG) * GPN;
  const unsigned short* hb = hbf_old + (size_t)g * N * 64;

  int rs[GPN + 1];
#pragma unroll
  for (int k = 0; k <= GPN; ++k) rs[k] = row_start[nb + k];

  // zero per-wave aggr staging (covers empty nodes)
#pragma unroll
  for (int k = 0; k < GPN; ++k) aggs[k * 64 + lane] = 0.f;

  // ================= edge phase (next-node col_s/ea prefetched) =================
  int k = 0;
  while (k < GPN && rs[k + 1] == rs[k]) ++k;
  int cnC = 0; float2 eaC = {0.f, 0.f};
  if (k < GPN) {
    int pos = rs[k] + cl; if (pos >= rs[k + 1]) pos = rs[k + 1] - 1;
    cnC = col_s[pos];
    eaC = ea_s[pos];
  }

  while (k < GPN) {
    // find next non-empty node; prefetch ONLY its col_s + ea (cheap, 4 regs)
    int kn = k + 1;
    while (kn < GPN && rs[kn + 1] == rs[kn]) ++kn;
    int cnN = 0; float2 eaX = {0.f, 0.f};
    if (kn < GPN) {
      int pos = rs[kn] + cl; if (pos >= rs[kn + 1]) pos = rs[kn + 1] - 1;
      cnN = col_s[pos];
      eaX = ea_s[pos];
    }

    const int es = rs[k], ee = rs[k + 1];
    const int deg = ee - es;
    float macc[4] = {0.f, 0.f, 0.f, 0.f};

    // node-row A-frags (broadcast loads, L1) -- independent of gather chain
    const unsigned short* pn = hb + (((size_t)(nb + k)) << 6) + hg * 8;
    const short8 av0 = *(const short8*)pn;
    const short8 av1 = *(const short8*)(pn + 32);

    // first tile gather: col index already in register (no col_s wait)
    const unsigned short* pc0 = hb + (((size_t)cnC) << 6) + hg * 8;
    short8 a2C = *(const short8*)pc0;
    short8 a3C = *(const short8*)(pc0 + 32);
    float2 eaCur = eaC;

    for (int ts = es; ts < ee; ts += 16) {
      const bool hasN = (ts + 16) < ee;
      float2 eaN; short8 a2N, a3N;
      if (hasN) {  // within-node prefetch (wave-uniform branch; multi-tile nodes)
        int p2 = ts + 16 + cl; if (p2 >= ee) p2 = ee - 1;
        eaN = ea_s[p2];
        const unsigned short* pc = hb + (((size_t)col_s[p2]) << 6) + hg * 8;
        a2N = *(const short8*)pc;
        a3N = *(const short8*)(pc + 32);
      }

      // GEMV1: K=128 (16 MFMA)
      f32x4 acc[4];
#pragma unroll
      for (int nt = 0; nt < 4; ++nt) acc[nt] = (f32x4){0.f, 0.f, 0.f, 0.f};
      __builtin_amdgcn_s_setprio(1);
#pragma unroll
      for (int nt = 0; nt < 4; ++nt)
        acc[nt] = __builtin_amdgcn_mfma_f32_16x16x32_bf16(av0, w1v[(nt * 4 + 0) * 64 + lane], acc[nt], 0, 0, 0);
#pragma unroll
      for (int nt = 0; nt < 4; ++nt)
        acc[nt] = __builtin_amdgcn_mfma_f32_16x16x32_bf16(av1, w1v[(nt * 4 + 1) * 64 + lane], acc[nt], 0, 0, 0);
#pragma unroll
      for (int nt = 0; nt < 4; ++nt)
        acc[nt] = __builtin_amdgcn_mfma_f32_16x16x32_bf16(a2C, w1v[(nt * 4 + 2) * 64 + lane], acc[nt], 0, 0, 0);
#pragma unroll
      for (int nt = 0; nt < 4; ++nt)
        acc[nt] = __builtin_amdgcn_mfma_f32_16x16x32_bf16(a3C, w1v[(nt * 4 + 3) * 64 + lane], acc[nt], 0, 0, 0);
      __builtin_amdgcn_s_setprio(0);

      // epilogue: bias + eattr; fused (sum,sumsq) LN; relu; P -> swizzled LDS
#pragma unroll
      for (int r = 0; r < 4; ++r) {
        const int edge = hg * 4 + r;
        float e0 = __shfl(eaCur.x, edge, 64);
        float e1 = __shfl(eaCur.y, edge, 64);
        float v[4];
#pragma unroll
        for (int nt = 0; nt < 4; ++nt)
          v[nt] = acc[nt][r] + b1c[nt] + e0 * wA[nt] + e1 * wB[nt];
        float s = v[0] + v[1] + v[2] + v[3];
        float q = v[0] * v[0] + v[1] * v[1] + v[2] * v[2] + v[3] * v[3];
#pragma unroll
        for (int o = 1; o < 16; o <<= 1) {
          s += __shfl_xor(s, o, 64);
          q += __shfl_xor(q, o, 64);
        }
        float mu = s * (1.f / 64.f);
        float var = fmaf(-mu, mu, q * (1.f / 64.f));
        float rsq = rsqrtf(var + EPS);
#pragma unroll
        for (int nt = 0; nt < 4; ++nt) {
          float p = fmaxf((v[nt] - mu) * rsq * g1c[nt] + be1c[nt], 0.f);
          unsigned byteoff = (unsigned)(edge * 128 + (nt * 16 + cl) * 2) ^ (unsigned)(hg << 5);
          *(unsigned short*)(pw + byteoff) = f2bf(p);
        }
      }

      // GEMV2 (8 MFMA)
      f32x4 m[4];
#pragma unroll
      for (int nt = 0; nt < 4; ++nt) m[nt] = (f32x4){0.f, 0.f, 0.f, 0.f};
      __builtin_amdgcn_s_setprio(1);
#pragma unroll
      for (int ks = 0; ks < 2; ++ks) {
        unsigned byteoff = (unsigned)(cl * 128 + (ks * 32 + hg * 8) * 2) ^ (unsigned)((cl >> 2) << 5);
        short8 a2 = *(const short8*)(pw + byteoff);
#pragma unroll
        for (int nt = 0; nt < 4; ++nt)
          m[nt] = __builtin_amdgcn_mfma_f32_16x16x32_bf16(
              a2, w2v[(nt * 2 + ks) * 64 + lane], m[nt], 0, 0, 0);
      }
      __builtin_amdgcn_s_setprio(0);

      // masked register accumulation (b2 folded later as deg*b2)
      const int vleft = ee - ts - hg * 4;
#pragma unroll
      for (int r = 0; r < 4; ++r) {
        if (r < vleft) {
#pragma unroll
          for (int nt = 0; nt < 4; ++nt) macc[nt] += m[nt][r];
        }
      }

      if (hasN) { eaCur = eaN; a2C = a2N; a3C = a3N; }
    }

    // node-k finalize: butterfly over hg, + deg*b2, store to swizzled aggs LDS
    float fin[4];
#pragma unroll
    for (int nt = 0; nt < 4; ++nt) {
      float s = macc[nt];
      s += __shfl_xor(s, 16, 64);
      s += __shfl_xor(s, 32, 64);
      fin[nt] = s + (float)deg * b2c[nt];
    }
    float sv = (hg == 0) ? fin[0] : (hg == 1) ? fin[1] : (hg == 2) ? fin[2] : fin[3];
    aggs[k * 64 + ((hg * 16 + cl) ^ (k << 3))] = sv;

    k = kn; cnC = cnN; eaC = eaX;
  }

  // ================= node phase: u = relu(LN([h,aggr]@uw+ub)); h += u =================
  {
    const int nc = (cl < GPN) ? cl : (GPN - 1);   // A row m = cl; rows >= GPN discarded
    const unsigned short* ph = hb + (((size_t)(nb + nc)) << 6) + hg * 8;
    short8 av[4];
    av[0] = *(const short8*)ph;
    av[1] = *(const short8*)(ph + 32);
    // aggr slices from swizzled LDS (contiguous after XOR since key is mult of 8)
    const int i0 = nc * 64 + ((hg * 8) ^ (nc << 3));
    const int i1 = nc * 64 + (((32 + hg * 8)) ^ (nc << 3));
    float4 q0 = *(const float4*)&aggs[i0];
    float4 q1 = *(const float4*)&aggs[i0 + 4];
    float4 q2 = *(const float4*)&aggs[i1];
    float4 q3 = *(const float4*)&aggs[i1 + 4];
    {
      union { short8 s; unsigned short u[8]; } t2, t3;
      t2.u[0] = f2bf(q0.x); t2.u[1] = f2bf(q0.y); t2.u[2] = f2bf(q0.z); t2.u[3] = f2bf(q0.w);
      t2.u[4] = f2bf(q1.x); t2.u[5] = f2bf(q1.y); t2.u[6] = f2bf(q1.z); t2.u[7] = f2bf(q1.w);
      t3.u[0] = f2bf(q2.x); t3.u[1] = f2bf(q2.y); t3.u[2] = f2bf(q2.z); t3.u[3] = f2bf(q2.w);
      t3.u[4] = f2bf(q3.x); t3.u[5] = f2bf(q3.y); t3.u[6] = f2bf(q3.z); t3.u[7] = f2bf(q3.w);
      av[2] = t2.s; av[3] = t3.s;
    }

    f32x4 acc[4];
#pragma unroll
    for (int nt = 0; nt < 4; ++nt) acc[nt] = (f32x4){0.f, 0.f, 0.f, 0.f};
    __builtin_amdgcn_s_setprio(1);
#pragma unroll
    for (int ks = 0; ks < 4; ++ks) {
#pragma unroll
      for (int nt = 0; nt < 4; ++nt)
        acc[nt] = __builtin_amdgcn_mfma_f32_16x16x32_bf16(
            av[ks], uwv[(nt * 4 + ks) * 64 + lane], acc[nt], 0, 0, 0);
    }
    __builtin_amdgcn_s_setprio(0);

    // epilogue: rows 0..GPN-1 live in hg==0 (row = hg*4+r)
#pragma unroll
    for (int r = 0; r < 4; ++r) {
      float v[4];
#pragma unroll
      for (int nt = 0; nt < 4; ++nt) v[nt] = acc[nt][r] + ubc[nt];
      float s = v[0] + v[1] + v[2] + v[3];
      float q = v[0] * v[0] + v[1] * v[1] + v[2] * v[2] + v[3] * v[3];
#pragma unroll
      for (int o = 1; o < 16; o <<= 1) {
        s += __shfl_xor(s, o, 64);
        q += __shfl_xor(q, o, 64);
      }
      float mu = s * (1.f / 64.f);
      float var = fmaf(-mu, mu, q * (1.f / 64.f));
      float rsq = rsqrtf(var + EPS);
      if (hg == 0) {
        const size_t nrow = ((size_t)(g * N + nb + r)) << 6;
#pragma unroll
        for (int nt = 0; nt < 4; ++nt) {
          int c = nt * 16 + cl;
          float u = fmaxf((v[nt] - mu) * rsq * ugc[nt] + ubec[nt], 0.f);
          float nv = h[nrow + c] + u;    // exclusive ownership -> in-place safe
          h[nrow + c] = nv;
          hbf_new[nrow + c] = f2bf(nv);
        }
      }
    }
  }
}

// ---------------- decoder ----------------
__global__ __launch_bounds__(512) void decoder_kernel(
    const float* __restrict__ h,
    const float* __restrict__ dw1, const float* __restrict__ db1,
    const float* __restrict__ dw2, const float* __restrict__ db2,
    float* __restrict__ out) {
  __shared__ __align__(16) float w1s[64 * 32];
  __shared__ float w2s[64];
  __shared__ float b1s[32];
  __shared__ float hs[8][64];
  const int tid = threadIdx.x;
  const int lane = tid & 63;
  const int w = tid >> 6;

  for (int idx = tid; idx < 64 * 32; idx += 512) w1s[idx] = dw1[idx];
  if (tid < 64) w2s[tid] = dw2[tid];
  if (tid < 32) b1s[tid] = db1[tid];
  const float ob0 = db2[0], ob1 = db2[1];
  __syncthreads();

  const int total = Bc * N;
  const int per_iter = gridDim.x * 8;
  const int niter = (total + per_iter - 1) / per_iter;
  const int wave_global = blockIdx.x * 8 + w;

  for (int it = 0; it < niter; ++it) {
    const int i = it * per_iter + wave_global;
    if (i < total) {
      hs[w][lane] = h[((size_t)i << 6) + lane];
      float s1 = 0.f;
      if (lane < 32) {
        s1 = b1s[lane];
        for (int k = 0; k < 64; ++k) s1 = fmaf(hs[w][k], w1s[k * 32 + lane], s1);
        s1 = fmaxf(s1, 0.f);
      }
      float c0 = (lane < 32) ? s1 * w2s[lane * 2]     : 0.f;
      float c1 = (lane < 32) ? s1 * w2s[lane * 2 + 1] : 0.f;
#pragma unroll
      for (int off = 16; off > 0; off >>= 1) {
        c0 += __shfl_xor(c0, off, 64);
        c1 += __shfl_xor(c1, off, 64);
      }
      if (lane == 0) {
        out[(size_t)i * 2]     = c0 + ob0;
        out[(size_t)i * 2 + 1] = c1 + ob1;
      }
    }
  }
}

extern "C" void kernel_launch(void* const* d_in, const int* in_sizes, int n_in,
                              void* d_out, int out_size, void* d_ws, size_t ws_size,
                              hipStream_t stream) {
  const float* x        = (const float*)d_in[0];
  const int*   ei       = (const int*)d_in[1];
  const float* eattr    = (const float*)d_in[2];
  const float* enc_w    = (const float*)d_in[3];
  const float* enc_b    = (const float*)d_in[4];
  const float* msg_w1   = (const float*)d_in[5];
  const float* msg_b1   = (const float*)d_in[6];
  const float* msg_ln_g = (const float*)d_in[7];
  const float* msg_ln_b = (const float*)d_in[8];
  const float* msg_w2   = (const float*)d_in[9];
  const float* msg_b2   = (const float*)d_in[10];
  const float* up_w     = (const float*)d_in[11];
  const float* up_b     = (const float*)d_in[12];
  const float* up_ln_g  = (const float*)d_in[13];
  const float* up_ln_b  = (const float*)d_in[14];
  const float* dw1      = (const float*)d_in[15];
  const float* db1      = (const float*)d_in[16];
  const float* dw2      = (const float*)d_in[17];
  const float* db2      = (const float*)d_in[18];
  float* out = (float*)d_out;

  // workspace: h (f32, in-place), hbf0/hbf1 (bf16 ping-pong), uw prepack, sorted arrays, CSR
  float* h              = (float*)d_ws;
  unsigned short* hbf0  = (unsigned short*)(h + (size_t)Bc * N * D);
  unsigned short* hbf1  = hbf0 + (size_t)Bc * N * D;
  unsigned short* uwpack = hbf1 + (size_t)Bc * N * D;            // L*16*512 bf16
  float2* ea_sv         = (float2*)(uwpack + (size_t)L * 16 * 512);
  int* col_sv           = (int*)(ea_sv + E);
  int* edge_order       = col_sv + E;
  int* deg              = edge_order + E;
  int* row_start        = deg + N;
  int* cursor           = row_start + N + 1;

  const int* row = ei;
  const int* col = ei + E;

  hipMemsetAsync(deg, 0, N * sizeof(int), stream);
  hist_kernel<<<(E + 255) / 256, 256, 0, stream>>>(row, deg);
  scan_kernel<<<1, 1024, 0, stream>>>(deg, row_start, cursor);
  scatter_kernel<<<(E + 255) / 256, 256, 0, stream>>>(row, cursor, edge_order);
  sortmap_kernel<<<(E + 255) / 256, 256, 0, stream>>>(edge_order, col, eattr, col_sv, ea_sv);
  packuw_kernel<<<dim3(16, L), 512, 0, stream>>>(up_w, uwpack);
  encoder_kernel<<<(Bc * N * D + 511) / 512, 512, 0, stream>>>(x, enc_w, enc_b, h, hbf0);

  unsigned short* hbufs[2] = {hbf0, hbf1};
  for (int l = 0; l < L; ++l) {
    layer_kernel<<<(NGRP + EWB - 1) / EWB, ETPB, 0, stream>>>(
        hbufs[l & 1], hbufs[(l + 1) & 1], h,
        col_sv, ea_sv, row_start,
        msg_w1 + (size_t)l * 130 * 64, msg_b1 + l * 64,
        msg_ln_g + l * 64, msg_ln_b + l * 64,
        msg_w2 + (size_t)l * 64 * 64, msg_b2 + l * 64,
        uwpack + (size_t)l * 16 * 512, up_b + l * 64,
        up_ln_g + l * 64, up_ln_b + l * 64);
  }

  decoder_kernel<<<512, 512, 0, stream>>>(h, dw1, db1, dw2, db2, out);
}

// Round 19
// 2440.816 us; speedup vs baseline: 1.5993x; 1.0718x over previous
//
#include <hip/hip_runtime.h>

constexpr int N = 20000;
constexpr int E = 320000;
constexpr int Bc = 2;
constexpr int D = 64;
constexpr int L = 25;
constexpr float EPS = 1e-5f;

typedef __attribute__((ext_vector_type(8))) short short8;
typedef __attribute__((ext_vector_type(4))) float f32x4;

__device__ __forceinline__ unsigned short f2bf(float f) {
  unsigned u = __float_as_uint(f);
  u += 0x7fff + ((u >> 16) & 1);   // RNE
  return (unsigned short)(u >> 16);
}

// ---------------- CSR build (once per launch; edges shared by both graphs) ----------------
__global__ void hist_kernel(const int* __restrict__ row, int* __restrict__ deg) {
  int e = blockIdx.x * blockDim.x + threadIdx.x;
  if (e < E) atomicAdd(&deg[row[e]], 1);
}

__global__ __launch_bounds__(1024) void scan_kernel(const int* __restrict__ deg,
                                                    int* __restrict__ row_start,
                                                    int* __restrict__ cursor) {
  __shared__ int s[1024];
  const int t = threadIdx.x;
  constexpr int CH = (N + 1023) / 1024;
  int base = t * CH;
  int sum = 0;
  for (int k = 0; k < CH; ++k) {
    int idx = base + k;
    if (idx < N) sum += deg[idx];
  }
  s[t] = sum;
  __syncthreads();
  for (int off = 1; off < 1024; off <<= 1) {
    int v = (t >= off) ? s[t - off] : 0;
    __syncthreads();
    s[t] += v;
    __syncthreads();
  }
  int excl = s[t] - sum;
  for (int k = 0; k < CH; ++k) {
    int idx = base + k;
    if (idx < N) {
      row_start[idx] = excl;
      cursor[idx] = excl;
      excl += deg[idx];
    }
  }
  if (t == 1023) row_start[N] = s[1023];
}

__global__ void scatter_kernel(const int* __restrict__ row, int* __restrict__ cursor,
                               int* __restrict__ edge_order) {
  int e = blockIdx.x * blockDim.x + threadIdx.x;
  if (e < E) {
    int p = atomicAdd(&cursor[row[e]], 1);
    edge_order[p] = e;
  }
}

__global__ void sortmap_kernel(const int* __restrict__ edge_order,
                               const int* __restrict__ col,
                               const float* __restrict__ eattr,
                               int* __restrict__ col_s, float2* __restrict__ ea_s) {
  int p = blockIdx.x * blockDim.x + threadIdx.x;
  if (p < E) {
    int eid = edge_order[p];
    col_s[p] = col[eid];
    ea_s[p] = *(const float2*)&eattr[2 * (size_t)eid];
  }
}

// ---------------- uw pre-pack: bf16 MFMA B-fragments, once ----------------
__global__ __launch_bounds__(512) void packuw_kernel(
    const float* __restrict__ up_w, unsigned short* __restrict__ uwpack) {
  const int f = blockIdx.x;   // 0..15
  const int l = blockIdx.y;   // 0..L-1
  const int t = threadIdx.x;  // 0..511
  const int ln = t >> 3, i = t & 7;
  int nt = f >> 2, ks = f & 3;
  int k = ks * 32 + (ln >> 4) * 8 + i, n = nt * 16 + (ln & 15);
  uwpack[((size_t)l * 16 + f) * 512 + ln * 8 + i] =
      f2bf(up_w[(size_t)l * 128 * 64 + (size_t)k * 64 + n]);
}

// ---------------- encoder ----------------
__global__ __launch_bounds__(512) void encoder_kernel(
    const float* __restrict__ x, const float* __restrict__ enc_w,
    const float* __restrict__ enc_b, float* __restrict__ h,
    unsigned short* __restrict__ hbf) {
  int idx = blockIdx.x * blockDim.x + threadIdx.x;
  if (idx >= Bc * N * D) return;
  int j = idx & (D - 1);
  int bn = idx >> 6;
  const float* xp = x + (size_t)bn * 3;
  float v = enc_b[j] + xp[0] * enc_w[j] + xp[1] * enc_w[D + j] + xp[2] * enc_w[2 * D + j];
  h[idx] = v;
  hbf[idx] = f2bf(v);
}

// ---------------- fused layer kernel: edge MLP + aggregate + node update ----------------
// R12 dataflow (known good, 2.45 ms) + T5 s_setprio around MFMA clusters.
constexpr int GPN = 4;              // nodes per wave
constexpr int GPG = N / GPN;        // 5000 groups per graph
constexpr int NGRP = GPG * Bc;      // 10000
constexpr int EWB = 8;              // waves per block
constexpr int ETPB = EWB * 64;      // 512

__global__ __launch_bounds__(ETPB, 4) void layer_kernel(
    const unsigned short* __restrict__ hbf_old, unsigned short* __restrict__ hbf_new,
    float* __restrict__ h,
    const int* __restrict__ col_s, const float2* __restrict__ ea_s,
    const int* __restrict__ row_start,
    const float* __restrict__ w1, const float* __restrict__ b1,
    const float* __restrict__ g1, const float* __restrict__ be1,
    const float* __restrict__ w2, const float* __restrict__ b2,
    const unsigned short* __restrict__ uwpack_l, const float* __restrict__ ub,
    const float* __restrict__ ug, const float* __restrict__ ube) {
  __shared__ __align__(16) char smem[24576 + EWB * 3072];  // 48 KB -> 3 blocks/CU
  unsigned short* w1f = (unsigned short*)smem;             // 16 KB (16 B-frags)
  unsigned short* w2f = (unsigned short*)(smem + 16384);   // 8 KB  (8 B-frags)

  const int tid = threadIdx.x, lane = tid & 63, w = tid >> 6;
  const int cl = lane & 15, hg = lane >> 4;
  char* pw = smem + 24576 + w * 3072;        // per-wave P staging (2 KB)
  float* aggs = (float*)(pw + 2048);         // per-wave aggr [GPN][64] f32 (1 KB)

  // B-frag staging: frag f; value wt[k][n], k=ks*32+(ln>>4)*8+i, n=nt*16+(ln&15)
  for (int idx = tid; idx < 16 * 512; idx += ETPB) {
    int f = idx >> 9, rem = idx & 511, ln = rem >> 3, i = rem & 7;
    int nt = f >> 2, ks = f & 3;
    int k = ks * 32 + (ln >> 4) * 8 + i, n = nt * 16 + (ln & 15);
    w1f[idx] = f2bf(w1[k * 64 + n]);
  }
  for (int idx = tid; idx < 8 * 512; idx += ETPB) {
    int f = idx >> 9, rem = idx & 511, ln = rem >> 3, i = rem & 7;
    int nt = f >> 1, ks = f & 1;
    int k = ks * 32 + (ln >> 4) * 8 + i, n = nt * 16 + (ln & 15);
    w2f[idx] = f2bf(w2[k * 64 + n]);
  }
  __syncthreads();  // only block-wide barrier

  float b1c[4], g1c[4], be1c[4], b2c[4], wA[4], wB[4], ubc[4], ugc[4], ubec[4];
#pragma unroll
  for (int nt = 0; nt < 4; ++nt) {
    int c = nt * 16 + cl;
    b1c[nt] = b1[c]; g1c[nt] = g1[c]; be1c[nt] = be1[c]; b2c[nt] = b2[c];
    wA[nt] = w1[128 * 64 + c]; wB[nt] = w1[129 * 64 + c];
    ubc[nt] = ub[c]; ugc[nt] = ug[c]; ubec[nt] = ube[c];
  }
  const short8* w1v = (const short8*)w1f;
  const short8* w2v = (const short8*)w2f;
  const short8* uwv = (const short8*)uwpack_l;   // L2-hot global frags

  const int gw = __builtin_amdgcn_readfirstlane(blockIdx.x * EWB + w);
  if (gw >= NGRP) return;
  const int g = (gw >= GPG) ? 1 : 0;
  const int nb = (gw - g * GPG) * GPN;
  const unsigned short* hb = hbf_old + (size_t)g * N * 64;

  int rs[GPN + 1];
#pragma unroll
  for (int k = 0; k <= GPN; ++k) rs[k] = row_start[nb + k];

  // zero per-wave aggr staging (covers empty nodes)
#pragma unroll
  for (int k = 0; k < GPN; ++k) aggs[k * 64 + lane] = 0.f;

  // ================= edge phase =================
  for (int k = 0; k < GPN; ++k) {
    const int es = rs[k], ee = rs[k + 1];
    const int deg = ee - es;
    if (deg == 0) continue;
    float macc[4] = {0.f, 0.f, 0.f, 0.f};

    // node-row A-frags (broadcast loads, L1)
    const unsigned short* pn = hb + (((size_t)(nb + k)) << 6) + hg * 8;
    const short8 av0 = *(const short8*)pn;
    const short8 av1 = *(const short8*)(pn + 32);

    // first tile gather
    int pos = es + cl; if (pos >= ee) pos = ee - 1;
    float2 eaC = ea_s[pos];
    const unsigned short* pc0 = hb + (((size_t)col_s[pos]) << 6) + hg * 8;
    short8 a2C = *(const short8*)pc0;
    short8 a3C = *(const short8*)(pc0 + 32);

    for (int ts = es; ts < ee; ts += 16) {
      const bool hasN = (ts + 16) < ee;
      float2 eaN; short8 a2N, a3N;
      if (hasN) {  // within-node prefetch (wave-uniform branch)
        int p2 = ts + 16 + cl; if (p2 >= ee) p2 = ee - 1;
        eaN = ea_s[p2];
        const unsigned short* pc = hb + (((size_t)col_s[p2]) << 6) + hg * 8;
        a2N = *(const short8*)pc;
        a3N = *(const short8*)(pc + 32);
      }

      // GEMV1: K=128 (16 MFMA)
      f32x4 acc[4];
#pragma unroll
      for (int nt = 0; nt < 4; ++nt) acc[nt] = (f32x4){0.f, 0.f, 0.f, 0.f};
      __builtin_amdgcn_s_setprio(1);
#pragma unroll
      for (int nt = 0; nt < 4; ++nt)
        acc[nt] = __builtin_amdgcn_mfma_f32_16x16x32_bf16(av0, w1v[(nt * 4 + 0) * 64 + lane], acc[nt], 0, 0, 0);
#pragma unroll
      for (int nt = 0; nt < 4; ++nt)
        acc[nt] = __builtin_amdgcn_mfma_f32_16x16x32_bf16(av1, w1v[(nt * 4 + 1) * 64 + lane], acc[nt], 0, 0, 0);
#pragma unroll
      for (int nt = 0; nt < 4; ++nt)
        acc[nt] = __builtin_amdgcn_mfma_f32_16x16x32_bf16(a2C, w1v[(nt * 4 + 2) * 64 + lane], acc[nt], 0, 0, 0);
#pragma unroll
      for (int nt = 0; nt < 4; ++nt)
        acc[nt] = __builtin_amdgcn_mfma_f32_16x16x32_bf16(a3C, w1v[(nt * 4 + 3) * 64 + lane], acc[nt], 0, 0, 0);
      __builtin_amdgcn_s_setprio(0);

      // epilogue: bias + eattr; fused (sum,sumsq) LN; relu; P -> swizzled LDS
#pragma unroll
      for (int r = 0; r < 4; ++r) {
        const int edge = hg * 4 + r;
        float e0 = __shfl(eaC.x, edge, 64);
        float e1 = __shfl(eaC.y, edge, 64);
        float v[4];
#pragma unroll
        for (int nt = 0; nt < 4; ++nt)
          v[nt] = acc[nt][r] + b1c[nt] + e0 * wA[nt] + e1 * wB[nt];
        float s = v[0] + v[1] + v[2] + v[3];
        float q = v[0] * v[0] + v[1] * v[1] + v[2] * v[2] + v[3] * v[3];
#pragma unroll
        for (int o = 1; o < 16; o <<= 1) {
          s += __shfl_xor(s, o, 64);
          q += __shfl_xor(q, o, 64);
        }
        float mu = s * (1.f / 64.f);
        float var = fmaf(-mu, mu, q * (1.f / 64.f));
        float rsq = rsqrtf(var + EPS);
#pragma unroll
        for (int nt = 0; nt < 4; ++nt) {
          float p = fmaxf((v[nt] - mu) * rsq * g1c[nt] + be1c[nt], 0.f);
          unsigned byteoff = (unsigned)(edge * 128 + (nt * 16 + cl) * 2) ^ (unsigned)(hg << 5);
          *(unsigned short*)(pw + byteoff) = f2bf(p);
        }
      }

      // GEMV2 (8 MFMA)
      f32x4 m[4];
#pragma unroll
      for (int nt = 0; nt < 4; ++nt) m[nt] = (f32x4){0.f, 0.f, 0.f, 0.f};
      __builtin_amdgcn_s_setprio(1);
#pragma unroll
      for (int ks = 0; ks < 2; ++ks) {
        unsigned byteoff = (unsigned)(cl * 128 + (ks * 32 + hg * 8) * 2) ^ (unsigned)((cl >> 2) << 5);
        short8 a2 = *(const short8*)(pw + byteoff);
#pragma unroll
        for (int nt = 0; nt < 4; ++nt)
          m[nt] = __builtin_amdgcn_mfma_f32_16x16x32_bf16(
              a2, w2v[(nt * 2 + ks) * 64 + lane], m[nt], 0, 0, 0);
      }
      __builtin_amdgcn_s_setprio(0);

      // masked register accumulation (b2 folded later as deg*b2)
      const int vleft = ee - ts - hg * 4;
#pragma unroll
      for (int r = 0; r < 4; ++r) {
        if (r < vleft) {
#pragma unroll
          for (int nt = 0; nt < 4; ++nt) macc[nt] += m[nt][r];
        }
      }

      if (hasN) { eaC = eaN; a2C = a2N; a3C = a3N; }
    }

    // node-k finalize: butterfly over hg, + deg*b2, store to swizzled aggs LDS
    float fin[4];
#pragma unroll
    for (int nt = 0; nt < 4; ++nt) {
      float s = macc[nt];
      s += __shfl_xor(s, 16, 64);
      s += __shfl_xor(s, 32, 64);
      fin[nt] = s + (float)deg * b2c[nt];
    }
    float sv = (hg == 0) ? fin[0] : (hg == 1) ? fin[1] : (hg == 2) ? fin[2] : fin[3];
    aggs[k * 64 + ((hg * 16 + cl) ^ (k << 3))] = sv;
  }

  // ================= node phase: u = relu(LN([h,aggr]@uw+ub)); h += u =================
  {
    const int nc = (cl < GPN) ? cl : (GPN - 1);   // A row m = cl; rows >= GPN discarded
    const unsigned short* ph = hb + (((size_t)(nb + nc)) << 6) + hg * 8;
    short8 av[4];
    av[0] = *(const short8*)ph;
    av[1] = *(const short8*)(ph + 32);
    // aggr slices from swizzled LDS (contiguous after XOR since key is mult of 8)
    const int i0 = nc * 64 + ((hg * 8) ^ (nc << 3));
    const int i1 = nc * 64 + (((32 + hg * 8)) ^ (nc << 3));
    float4 q0 = *(const float4*)&aggs[i0];
    float4 q1 = *(const float4*)&aggs[i0 + 4];
    float4 q2 = *(const float4*)&aggs[i1];
    float4 q3 = *(const float4*)&aggs[i1 + 4];
    {
      union { short8 s; unsigned short u[8]; } t2, t3;
      t2.u[0] = f2bf(q0.x); t2.u[1] = f2bf(q0.y); t2.u[2] = f2bf(q0.z); t2.u[3] = f2bf(q0.w);
      t2.u[4] = f2bf(q1.x); t2.u[5] = f2bf(q1.y); t2.u[6] = f2bf(q1.z); t2.u[7] = f2bf(q1.w);
      t3.u[0] = f2bf(q2.x); t3.u[1] = f2bf(q2.y); t3.u[2] = f2bf(q2.z); t3.u[3] = f2bf(q2.w);
      t3.u[4] = f2bf(q3.x); t3.u[5] = f2bf(q3.y); t3.u[6] = f2bf(q3.z); t3.u[7] = f2bf(q3.w);
      av[2] = t2.s; av[3] = t3.s;
    }

    f32x4 acc[4];
#pragma unroll
    for (int nt = 0; nt < 4; ++nt) acc[nt] = (f32x4){0.f, 0.f, 0.f, 0.f};
    __builtin_amdgcn_s_setprio(1);
#pragma unroll
    for (int ks = 0; ks < 4; ++ks) {
#pragma unroll
      for (int nt = 0; nt < 4; ++nt)
        acc[nt] = __builtin_amdgcn_mfma_f32_16x16x32_bf16(
            av[ks], uwv[(nt * 4 + ks) * 64 + lane], acc[nt], 0, 0, 0);
    }
    __builtin_amdgcn_s_setprio(0);

    // epilogue: rows 0..GPN-1 live in hg==0 (row = hg*4+r)
#pragma unroll
    for (int r = 0; r < 4; ++r) {
      float v[4];
#pragma unroll
      for (int nt = 0; nt < 4; ++nt) v[nt] = acc[nt][r] + ubc[nt];
      float s = v[0] + v[1] + v[2] + v[3];
      float q = v[0] * v[0] + v[1] * v[1] + v[2] * v[2] + v[3] * v[3];
#pragma unroll
      for (int o = 1; o < 16; o <<= 1) {
        s += __shfl_xor(s, o, 64);
        q += __shfl_xor(q, o, 64);
      }
      float mu = s * (1.f / 64.f);
      float var = fmaf(-mu, mu, q * (1.f / 64.f));
      float rsq = rsqrtf(var + EPS);
      if (hg == 0) {
        const size_t nrow = ((size_t)(g * N + nb + r)) << 6;
#pragma unroll
        for (int nt = 0; nt < 4; ++nt) {
          int c = nt * 16 + cl;
          float u = fmaxf((v[nt] - mu) * rsq * ugc[nt] + ubec[nt], 0.f);
          float nv = h[nrow + c] + u;    // exclusive ownership -> in-place safe
          h[nrow + c] = nv;
          hbf_new[nrow + c] = f2bf(nv);
        }
      }
    }
  }
}

// ---------------- decoder ----------------
__global__ __launch_bounds__(512) void decoder_kernel(
    const float* __restrict__ h,
    const float* __restrict__ dw1, const float* __restrict__ db1,
    const float* __restrict__ dw2, const float* __restrict__ db2,
    float* __restrict__ out) {
  __shared__ __align__(16) float w1s[64 * 32];
  __shared__ float w2s[64];
  __shared__ float b1s[32];
  __shared__ float hs[8][64];
  const int tid = threadIdx.x;
  const int lane = tid & 63;
  const int w = tid >> 6;

  for (int idx = tid; idx < 64 * 32; idx += 512) w1s[idx] = dw1[idx];
  if (tid < 64) w2s[tid] = dw2[tid];
  if (tid < 32) b1s[tid] = db1[tid];
  const float ob0 = db2[0], ob1 = db2[1];
  __syncthreads();

  const int total = Bc * N;
  const int per_iter = gridDim.x * 8;
  const int niter = (total + per_iter - 1) / per_iter;
  const int wave_global = blockIdx.x * 8 + w;

  for (int it = 0; it < niter; ++it) {
    const int i = it * per_iter + wave_global;
    if (i < total) {
      hs[w][lane] = h[((size_t)i << 6) + lane];
      float s1 = 0.f;
      if (lane < 32) {
        s1 = b1s[lane];
        for (int k = 0; k < 64; ++k) s1 = fmaf(hs[w][k], w1s[k * 32 + lane], s1);
        s1 = fmaxf(s1, 0.f);
      }
      float c0 = (lane < 32) ? s1 * w2s[lane * 2]     : 0.f;
      float c1 = (lane < 32) ? s1 * w2s[lane * 2 + 1] : 0.f;
#pragma unroll
      for (int off = 16; off > 0; off >>= 1) {
        c0 += __shfl_xor(c0, off, 64);
        c1 += __shfl_xor(c1, off, 64);
      }
      if (lane == 0) {
        out[(size_t)i * 2]     = c0 + ob0;
        out[(size_t)i * 2 + 1] = c1 + ob1;
      }
    }
  }
}

extern "C" void kernel_launch(void* const* d_in, const int* in_sizes, int n_in,
                              void* d_out, int out_size, void* d_ws, size_t ws_size,
                              hipStream_t stream) {
  const float* x        = (const float*)d_in[0];
  const int*   ei       = (const int*)d_in[1];
  const float* eattr    = (const float*)d_in[2];
  const float* enc_w    = (const float*)d_in[3];
  const float* enc_b    = (const float*)d_in[4];
  const float* msg_w1   = (const float*)d_in[5];
  const float* msg_b1   = (const float*)d_in[6];
  const float* msg_ln_g = (const float*)d_in[7];
  const float* msg_ln_b = (const float*)d_in[8];
  const float* msg_w2   = (const float*)d_in[9];
  const float* msg_b2   = (const float*)d_in[10];
  const float* up_w     = (const float*)d_in[11];
  const float* up_b     = (const float*)d_in[12];
  const float* up_ln_g  = (const float*)d_in[13];
  const float* up_ln_b  = (const float*)d_in[14];
  const float* dw1      = (const float*)d_in[15];
  const float* db1      = (const float*)d_in[16];
  const float* dw2      = (const float*)d_in[17];
  const float* db2      = (const float*)d_in[18];
  float* out = (float*)d_out;

  // workspace: h (f32, in-place), hbf0/hbf1 (bf16 ping-pong), uw prepack, sorted arrays, CSR
  float* h              = (float*)d_ws;
  unsigned short* hbf0  = (unsigned short*)(h + (size_t)Bc * N * D);
  unsigned short* hbf1  = hbf0 + (size_t)Bc * N * D;
  unsigned short* uwpack = hbf1 + (size_t)Bc * N * D;            // L*16*512 bf16
  float2* ea_sv         = (float2*)(uwpack + (size_t)L * 16 * 512);
  int* col_sv           = (int*)(ea_sv + E);
  int* edge_order       = col_sv + E;
  int* deg              = edge_order + E;
  int* row_start        = deg + N;
  int* cursor           = row_start + N + 1;

  const int* row = ei;
  const int* col = ei + E;

  hipMemsetAsync(deg, 0, N * sizeof(int), stream);
  hist_kernel<<<(E + 255) / 256, 256, 0, stream>>>(row, deg);
  scan_kernel<<<1, 1024, 0, stream>>>(deg, row_start, cursor);
  scatter_kernel<<<(E + 255) / 256, 256, 0, stream>>>(row, cursor, edge_order);
  sortmap_kernel<<<(E + 255) / 256, 256, 0, stream>>>(edge_order, col, eattr, col_sv, ea_sv);
  packuw_kernel<<<dim3(16, L), 512, 0, stream>>>(up_w, uwpack);
  encoder_kernel<<<(Bc * N * D + 511) / 512, 512, 0, stream>>>(x, enc_w, enc_b, h, hbf0);

  unsigned short* hbufs[2] = {hbf0, hbf1};
  for (int l = 0; l < L; ++l) {
    layer_kernel<<<(NGRP + EWB - 1) / EWB, ETPB, 0, stream>>>(
        hbufs[l & 1], hbufs[(l + 1) & 1], h,
        col_sv, ea_sv, row_start,
        msg_w1 + (size_t)l * 130 * 64, msg_b1 + l * 64,
        msg_ln_g + l * 64, msg_ln_b + l * 64,
        msg_w2 + (size_t)l * 64 * 64, msg_b2 + l * 64,
        uwpack + (size_t)l * 16 * 512, up_b + l * 64,
        up_ln_g + l * 64, up_ln_b + l * 64);
  }

  decoder_kernel<<<512, 512, 0, stream>>>(h, dw1, db1, dw2, db2, out);
}